// Round 12
// baseline (421.303 us; speedup 1.0000x reference)
//
#include <hip/hip_runtime.h>

#define BB 32
#define CC 1024
#define EE 256

typedef __attribute__((ext_vector_type(8))) short bf16x8;
typedef __attribute__((ext_vector_type(16))) float f32x16;

__device__ __forceinline__ ushort f2bf(float f) {
    unsigned u = __float_as_uint(f);
    unsigned r = (u + 0x7FFFu + ((u >> 16) & 1u)) >> 16;
    return (ushort)r;
}
__device__ __forceinline__ float bf2f(ushort u) { return __uint_as_float((unsigned)u << 16); }

// packed f32x2 -> bf16x2 (RNE, identical to f2bf) — no builtin on gfx950, use asm
__device__ __forceinline__ unsigned cvtpk(float lo, float hi) {
    unsigned r;
    asm("v_cvt_pk_bf16_f32 %0, %1, %2" : "=v"(r) : "v"(lo), "v"(hi));
    return r;
}

// stage 128 rows x 64 bf16 (128B) from global into 16KB LDS, source pre-swizzled so that
// ds_read with chunk ^= (row&7) returns linear data. LDS dest must be wave-uniform.
__device__ __forceinline__ void stage16(const char* srcBase, long stride, ushort* ldsBase,
                                        int wid, int lane) {
    #pragma unroll
    for (int i = 0; i < 4; ++i) {
        int gch = (wid * 4 + i) * 64 + lane;
        int row = gch >> 3, cj = gch & 7;
        const char* src = srcBase + (long)row * stride + ((cj ^ (row & 7)) << 4);
        __builtin_amdgcn_global_load_lds(
            (const __attribute__((address_space(1))) unsigned*)src,
            (__attribute__((address_space(3))) unsigned*)(ldsBase + (wid * 4 + i) * 512),
            16, 0, 0);
    }
}

__device__ __forceinline__ bf16x8 frag(const ushort* L, int row, int kc) {
    return *(const bf16x8*)&L[row * 64 + ((kc ^ (row & 7)) << 3)];
}

// ---------------- K1: SE adaptive-avg-pool
__global__ __launch_bounds__(256) void k_pool(const float* __restrict__ x,
                                              float* __restrict__ y0) {
    int t = threadIdx.x;
    int lane = t & 63;
    int v = blockIdx.x * 4 + (t >> 6);
    const float2* p = (const float2*)(x + (size_t)v * 128);
    float2 d = p[lane];
    float s = d.x + d.y;
    #pragma unroll
    for (int m = 1; m < 64; m <<= 1) s += __shfl_xor(s, m, 64);
    if (lane == 0) y0[v] = s * (1.0f / 128.0f);
}

// ---------------- K2: fused SE fc1+fc2 (block per batch) + Wcat/wsb prep tail blocks
__global__ __launch_bounds__(1024) void k_se(const float* __restrict__ y0,
                                             const float* __restrict__ w1,
                                             const float* __restrict__ w2,
                                             float* __restrict__ yy,
                                             const float* __restrict__ W,
                                             const float* __restrict__ theta,
                                             const float* __restrict__ wsi,
                                             ushort* __restrict__ Wcat,
                                             ushort* __restrict__ wsb) {
    int t = threadIdx.x;
    if (blockIdx.x >= 32) {
        int idx = (blockIdx.x - 32) * 1024 + t;
        if (idx < 262144) {
            int n = idx >> 8, k = idx & 255;
            float v;
            if (n < 512) v = W[n * 256 + k];
            else if (n < 768) v = theta[k * 256 + (n - 512)];
            else v = theta[65536 + k * 256 + (n - 768)];
            Wcat[idx] = f2bf(v);
        } else {
            int i2 = idx - 262144;          // 0..32767 -> ws [256 e][128 l] plain bf16
            wsb[i2] = f2bf(wsi[i2]);
        }
        return;
    }
    __shared__ float buf[1024];
    __shared__ float buf2[1024];
    int b = blockIdx.x;
    buf[t] = y0[b * 1024 + t];
    __syncthreads();
    {   // fc1 + relu
        const float4* wr = (const float4*)(w1 + (size_t)t * 1024);
        float acc = 0.f;
        #pragma unroll 4
        for (int c4 = 0; c4 < 256; ++c4) {
            float4 wv = wr[c4];
            const float* yv = &buf[c4 * 4];
            acc += wv.x * yv[0] + wv.y * yv[1] + wv.z * yv[2] + wv.w * yv[3];
        }
        buf2[t] = fmaxf(acc, 0.f);
    }
    __syncthreads();
    {   // fc2 + sigmoid
        const float4* wr = (const float4*)(w2 + (size_t)t * 1024);
        float acc = 0.f;
        #pragma unroll 4
        for (int c4 = 0; c4 < 256; ++c4) {
            float4 wv = wr[c4];
            const float* yv = &buf2[c4 * 4];
            acc += wv.x * yv[0] + wv.y * yv[1] + wv.z * yv[2] + wv.w * yv[3];
        }
        yy[b * 1024 + t] = 1.f / (1.f + expf(-acc));
    }
}

// ---------------- K4: SE-scale + 1x1 conv as MFMA GEMM.
// Block (b, 64-c tile): xg[c,e] = sum_l (x[l,c]*y[8l+cb]) * ws[e,l].
__global__ __launch_bounds__(256) void k_conv(const float* __restrict__ x,
                                              const ushort* __restrict__ wsb,
                                              const float* __restrict__ y,
                                              ushort* __restrict__ xgb) {
    __shared__ __align__(16) ushort wsB[256 * 64];   // [e][l-half] swizzled, 32KB
    __shared__ __align__(16) ushort xfB[64 * 72];    // [l-half][c] staging, 9KB
    __shared__ __align__(16) ushort xT[64 * 64];     // [c][l-half] swizzled, 8KB
    __shared__ float sl[128];
    int bid = blockIdx.x;
    int b = bid >> 4, ct = bid & 15;
    int c0 = ct * 64, cb = ct >> 1;
    int t = threadIdx.x, wid = t >> 6, l = t & 63;
    int ln = l & 31, hi = l >> 5;

    if (t < 128) sl[t] = y[b * 1024 + 8 * t + cb];

    f32x16 acc[2][2];
    #pragma unroll
    for (int i = 0; i < 2; ++i)
        #pragma unroll
        for (int j = 0; j < 2; ++j)
            #pragma unroll
            for (int q = 0; q < 16; ++q) acc[i][j][q] = 0.f;

    for (int ph = 0; ph < 2; ++ph) {
        int lh = ph * 64;
        __syncthreads();
        #pragma unroll
        for (int i = 0; i < 8; ++i) {
            int gch = i * 256 + wid * 64 + l;
            int e = gch >> 3, cj = gch & 7;
            const ushort* src = wsb + e * 128 + lh + ((cj ^ (e & 7)) << 3);
            __builtin_amdgcn_global_load_lds(
                (const __attribute__((address_space(1))) unsigned*)src,
                (__attribute__((address_space(3))) unsigned*)(wsB + gch * 8),
                16, 0, 0);
        }
        #pragma unroll
        for (int i = 0; i < 4; ++i) {
            int chunk = i * 256 + t;
            int lr = chunk >> 4, cq = chunk & 15;
            float4 v = *(const float4*)&x[(size_t)b * 131072 + (size_t)(lh + lr) * 1024 + c0 + cq * 4];
            float s = sl[lh + lr];
            uint2 pk;
            pk.x = cvtpk(v.x * s, v.y * s);
            pk.y = cvtpk(v.z * s, v.w * s);
            *(uint2*)&xfB[lr * 72 + cq * 4] = pk;
        }
        __syncthreads();
        {
            int c = t & 63, lq = t >> 6;
            #pragma unroll
            for (int q2 = 0; q2 < 2; ++q2) {
                int cj = lq * 2 + q2;
                bf16x8 pk;
                #pragma unroll
                for (int jj = 0; jj < 8; ++jj)
                    pk[jj] = (short)xfB[(cj * 8 + jj) * 72 + c];
                *(bf16x8*)&xT[c * 64 + ((cj ^ (c & 7)) << 3)] = pk;
            }
        }
        __syncthreads();
        __builtin_amdgcn_s_setprio(1);
        #pragma unroll
        for (int ks = 0; ks < 4; ++ks) {
            int kc = ks * 2 + hi;
            bf16x8 a0 = frag(xT, ln, kc);
            bf16x8 a1 = frag(xT, ln + 32, kc);
            bf16x8 b0 = frag(wsB, wid * 64 + ln, kc);
            bf16x8 b1 = frag(wsB, wid * 64 + 32 + ln, kc);
            acc[0][0] = __builtin_amdgcn_mfma_f32_32x32x16_bf16(a0, b0, acc[0][0], 0, 0, 0);
            acc[0][1] = __builtin_amdgcn_mfma_f32_32x32x16_bf16(a0, b1, acc[0][1], 0, 0, 0);
            acc[1][0] = __builtin_amdgcn_mfma_f32_32x32x16_bf16(a1, b0, acc[1][0], 0, 0, 0);
            acc[1][1] = __builtin_amdgcn_mfma_f32_32x32x16_bf16(a1, b1, acc[1][1], 0, 0, 0);
        }
        __builtin_amdgcn_s_setprio(0);
    }
    #pragma unroll
    for (int mi = 0; mi < 2; ++mi)
        #pragma unroll
        for (int ni = 0; ni < 2; ++ni) {
            int e = wid * 64 + ni * 32 + ln;
            #pragma unroll
            for (int r2 = 0; r2 < 4; ++r2)
                #pragma unroll
                for (int j = 0; j < 4; ++j) {
                    int cloc = mi * 32 + 8 * r2 + 4 * hi + j;
                    xgb[(size_t)(b * 1024 + c0 + cloc) * 256 + e] = f2bf(acc[mi][ni][r2 * 4 + j]);
                }
        }
}

// ---------------- K5: projection GEMM (qk + xt1T only; xt0 folded into mm2).
// grid 1536: 6 n-tiles per 128-row m-strip. nt<4 -> qk(+bias), nt 4,5 -> xt1T.
// xt1T tiles read theta1 rows of Wcat (768+): B row base n0+256.
__global__ __launch_bounds__(256) void k_mm1(const ushort* __restrict__ xgb,
                                             const ushort* __restrict__ Wcat,
                                             const float* __restrict__ bias,
                                             ushort* __restrict__ qk,
                                             ushort* __restrict__ xt1T) {
    __shared__ __align__(16) ushort smem[32768];   // 2 bufs x (Al 8192 + Bl 8192)
    int d = blockIdx.x;
    int xcd = d & 7, r = d >> 3;
    int q6 = r / 6;
    int mt = xcd * 32 + q6, nt = r - q6 * 6;
    int m0 = mt * 128, n0 = nt * 128;
    int bn0 = (nt < 4) ? n0 : n0 + 256;            // theta1 rows for xt1T tiles
    int t = threadIdx.x, wid = t >> 6, l = t & 63;
    int ln = l & 31, hi = l >> 5;
    int wr = wid >> 1, wc = wid & 1;
    const char* Ab = (const char*)xgb + (size_t)m0 * 512;
    const char* Bb = (const char*)Wcat + (size_t)bn0 * 512;
    f32x16 acc[2][2];
    #pragma unroll
    for (int i = 0; i < 2; ++i)
        #pragma unroll
        for (int j = 0; j < 2; ++j)
            #pragma unroll
            for (int q = 0; q < 16; ++q) acc[i][j][q] = 0.f;

    stage16(Ab, 512, smem, wid, l);
    stage16(Bb, 512, smem + 8192, wid, l);
    __syncthreads();
    for (int kt = 0; kt < 4; ++kt) {
        const ushort* Al = smem + (kt & 1) * 16384;
        const ushort* Bl = Al + 8192;
        if (kt < 3) {
            ushort* nb = smem + ((kt + 1) & 1) * 16384;
            stage16(Ab + (kt + 1) * 128, 512, nb, wid, l);
            stage16(Bb + (kt + 1) * 128, 512, nb + 8192, wid, l);
        }
        __builtin_amdgcn_s_setprio(1);
        #pragma unroll
        for (int ks = 0; ks < 4; ++ks) {
            int kc = ks * 2 + hi;
            int mr = wr * 64 + ln, nr = wc * 64 + ln;
            bf16x8 a0 = frag(Al, mr, kc);
            bf16x8 a1 = frag(Al, mr + 32, kc);
            bf16x8 b0 = frag(Bl, nr, kc);
            bf16x8 b1 = frag(Bl, nr + 32, kc);
            acc[0][0] = __builtin_amdgcn_mfma_f32_32x32x16_bf16(a0, b0, acc[0][0], 0, 0, 0);
            acc[0][1] = __builtin_amdgcn_mfma_f32_32x32x16_bf16(a0, b1, acc[0][1], 0, 0, 0);
            acc[1][0] = __builtin_amdgcn_mfma_f32_32x32x16_bf16(a1, b0, acc[1][0], 0, 0, 0);
            acc[1][1] = __builtin_amdgcn_mfma_f32_32x32x16_bf16(a1, b1, acc[1][1], 0, 0, 0);
        }
        __builtin_amdgcn_s_setprio(0);
        __syncthreads();
    }
    if (nt < 4) {
        float bv[2];
        bv[0] = bias[nt * 128 + wc * 64 + ln];
        bv[1] = bias[nt * 128 + wc * 64 + 32 + ln];
        #pragma unroll
        for (int mi = 0; mi < 2; ++mi)
            #pragma unroll
            for (int ni = 0; ni < 2; ++ni) {
                int ncol = wc * 64 + ni * 32 + ln;
                #pragma unroll
                for (int r2 = 0; r2 < 4; ++r2)
                    #pragma unroll
                    for (int j = 0; j < 4; ++j) {
                        int mloc = wr * 64 + mi * 32 + 8 * r2 + 4 * hi + j;
                        float v = acc[mi][ni][r2 * 4 + j] + bv[ni];
                        size_t m = (size_t)(m0 + mloc);
                        qk[m * 512 + nt * 128 + ncol] = f2bf(v);
                    }
            }
    } else {
        ushort* Tl = smem;   // [128][136]
        #pragma unroll
        for (int mi = 0; mi < 2; ++mi)
            #pragma unroll
            for (int ni = 0; ni < 2; ++ni) {
                int nl = wc * 64 + ni * 32 + ln;
                #pragma unroll
                for (int r2 = 0; r2 < 4; ++r2) {
                    int mbase = wr * 64 + mi * 32 + 8 * r2 + 4 * hi;
                    ushort4 pk = make_ushort4(f2bf(acc[mi][ni][r2 * 4 + 0]),
                                              f2bf(acc[mi][ni][r2 * 4 + 1]),
                                              f2bf(acc[mi][ni][r2 * 4 + 2]),
                                              f2bf(acc[mi][ni][r2 * 4 + 3]));
                    *(ushort4*)&Tl[nl * 136 + mbase] = pk;
                }
            }
        __syncthreads();
        int n = t >> 1, mh = (t & 1) * 64;
        int bq = m0 >> 10, mib = m0 & 1023;
        ushort* dst = xt1T + (((size_t)(bq * 256 + (nt - 4) * 128 + n)) << 10) + mib + mh;
        #pragma unroll
        for (int j = 0; j < 8; ++j)
            *(uint4*)(dst + j * 8) = *(const uint4*)&Tl[n * 136 + mh + j * 8];
    }
}

// ---------------- K6a: attention partial exp-sums (head-pair split).
// grid 2048. XCD-local decode: bid&7 = b&7.
__global__ __launch_bounds__(256, 3) void k_attn_s(const ushort* __restrict__ qkb,
                                                   float* __restrict__ sums) {
    __shared__ __align__(16) ushort klds[2][4096];       // [buf][32 keys][128 d swz]
    const float SCL2 = 0.18033688011112042f;             // log2(e)/8
    int bid = blockIdx.x;
    int b = ((bid >> 3) & 3) * 8 + (bid & 7);
    int hp = (bid >> 5) & 1;
    int kh = (bid >> 6) & 3;
    int qt = bid >> 8;
    int t = threadIdx.x, g = t >> 6, l = t & 63;
    int wid = g;
    int col = l & 31, hi = l >> 5;
    size_t qbase = (size_t)b * 1024 * 512;
    int qrow = qt * 128 + g * 32 + col;
    int key0 = kh * 256;

    bf16x8 qa[2][4];
    #pragma unroll
    for (int hh = 0; hh < 2; ++hh)
        #pragma unroll
        for (int kk = 0; kk < 4; ++kk)
            qa[hh][kk] = *(const bf16x8*)&qkb[qbase + (size_t)qrow * 512 +
                                             (hp * 2 + hh) * 64 + kk * 16 + hi * 8];

    const char* kgb = (const char*)(qkb + qbase + 256 + hp * 128);
    auto stage_k = [&](int kt, ushort* dst) {
        #pragma unroll
        for (int i = 0; i < 2; ++i) {
            int gidx = i * 256 + wid * 64 + l;
            int row = gidx >> 4, c = gidx & 15;
            const char* src = kgb + (size_t)(key0 + kt * 32 + row) * 1024 +
                              (((c >> 3) << 7) + (((c & 7) ^ (row & 7)) << 4));
            __builtin_amdgcn_global_load_lds(
                (const __attribute__((address_space(1))) unsigned*)src,
                (__attribute__((address_space(3))) unsigned*)(dst + (i * 256 + wid * 64) * 8),
                16, 0, 0);
        }
    };

    float prsum[2][16];
    #pragma unroll
    for (int hh = 0; hh < 2; ++hh)
        #pragma unroll
        for (int r = 0; r < 16; ++r) prsum[hh][r] = 0.f;

    stage_k(0, klds[0]);
    __syncthreads();
    for (int kt = 0; kt < 8; ++kt) {
        if (kt < 7) stage_k(kt + 1, klds[(kt + 1) & 1]);
        const ushort* kl = &klds[kt & 1][0];
        f32x16 acc[2];
        #pragma unroll
        for (int hh = 0; hh < 2; ++hh)
            #pragma unroll
            for (int r = 0; r < 16; ++r) acc[hh][r] = 0.f;
        __builtin_amdgcn_s_setprio(1);
        #pragma unroll
        for (int kk = 0; kk < 4; ++kk) {
            #pragma unroll
            for (int hh = 0; hh < 2; ++hh) {
                bf16x8 kb = *(const bf16x8*)&kl[col * 128 +
                                               (hh * 8 + ((kk * 2 + hi) ^ (col & 7))) * 8];
                acc[hh] = __builtin_amdgcn_mfma_f32_32x32x16_bf16(qa[hh][kk], kb, acc[hh], 0, 0, 0);
            }
        }
        __builtin_amdgcn_s_setprio(0);
        #pragma unroll
        for (int hh = 0; hh < 2; ++hh)
            #pragma unroll
            for (int r = 0; r < 16; ++r)
                prsum[hh][r] += exp2f(acc[hh][r] * SCL2);
        __syncthreads();
    }
    #pragma unroll
    for (int hh = 0; hh < 2; ++hh)
        #pragma unroll
        for (int r = 0; r < 16; ++r) {
            float s = prsum[hh][r];
            s += __shfl_xor(s, 1, 64);
            s += __shfl_xor(s, 2, 64);
            s += __shfl_xor(s, 4, 64);
            s += __shfl_xor(s, 8, 64);
            s += __shfl_xor(s, 16, 64);
            prsum[hh][r] = s;
        }
    if (col == 0) {
        int rowbase = qt * 128 + g * 32 + 4 * hi;
        #pragma unroll
        for (int hh = 0; hh < 2; ++hh)
            #pragma unroll
            for (int r = 0; r < 16; ++r) {
                int row = rowbase + (r & 3) + 8 * (r >> 2);
                sums[(((size_t)b * 1024 + row) * 4 + hp * 2 + hh) * 4 + kh] = prsum[hh][r];
            }
    }
}

// ---------------- K6b: attention normalize + write b_adj fp32.
// grid 1024, XCD-local. Head-sequential MFMA with C-init log-bias.
__global__ __launch_bounds__(256, 3) void k_attn_w(const ushort* __restrict__ qkb,
                                                   const float* __restrict__ sums,
                                                   float* __restrict__ badj) {
    __shared__ __align__(16) ushort klds[2][8192];
    __shared__ __align__(16) float biasB[4][128];
    const float SCL2 = 0.18033688011112042f;
    const float INV_SCL2 = 5.545177444479562f;           // 1/SCL2
    int bid = blockIdx.x;
    int b = ((bid >> 3) & 3) * 8 + (bid & 7);
    int kh = (bid >> 5) & 3;
    int qt = bid >> 7;
    int t = threadIdx.x, g = t >> 6, l = t & 63;
    int wid = g;
    int col = l & 31, hi = l >> 5;
    size_t qbase = (size_t)b * 1024 * 512;
    int qrow = qt * 128 + g * 32 + col;
    int key0 = kh * 256;

    {
        const float4* sp = (const float4*)(sums + ((size_t)b * 1024 + qt * 128) * 16);
        #pragma unroll
        for (int i = 0; i < 2; ++i) {
            int f = t * 2 + i;
            float4 v = sp[f];
            float s4 = v.x + v.y + v.z + v.w;
            biasB[f & 3][f >> 2] = -(__log2f(s4) + 2.0f) * INV_SCL2;
        }
    }

    bf16x8 qa[4][4];
    #pragma unroll
    for (int h = 0; h < 4; ++h)
        #pragma unroll
        for (int kk = 0; kk < 4; ++kk)
            qa[h][kk] = *(const bf16x8*)&qkb[qbase + (size_t)qrow * 512 + h * 64 + kk * 16 + hi * 8];

    const char* kgb = (const char*)(qkb + qbase + 256);
    auto stage_k = [&](int kt, ushort* dst) {
        #pragma unroll
        for (int i = 0; i < 4; ++i) {
            int gidx = i * 256 + wid * 64 + l;
            int row = gidx >> 5, c = gidx & 31;
            const char* src = kgb + (size_t)(key0 + kt * 32 + row) * 1024 +
                              (((c >> 3) << 7) + (((c & 7) ^ (row & 7)) << 4));
            __builtin_amdgcn_global_load_lds(
                (const __attribute__((address_space(1))) unsigned*)src,
                (__attribute__((address_space(3))) unsigned*)(dst + (i * 256 + wid * 64) * 8),
                16, 0, 0);
        }
    };

    stage_k(0, klds[0]);
    __syncthreads();

    float* orow = badj + ((size_t)b << 20) + (size_t)(qt * 128 + g * 32) * 1024;
    for (int kt = 0; kt < 8; ++kt) {
        if (kt < 7) stage_k(kt + 1, klds[(kt + 1) & 1]);
        const ushort* kl = &klds[kt & 1][0];
        float vsum[16];
        #pragma unroll
        for (int r = 0; r < 16; ++r) vsum[r] = 0.f;
        #pragma unroll
        for (int h = 0; h < 4; ++h) {
            f32x16 acc;
            #pragma unroll
            for (int g2 = 0; g2 < 4; ++g2) {
                float4 ib = *(const float4*)&biasB[h][g * 32 + g2 * 8 + 4 * hi];
                acc[g2 * 4 + 0] = ib.x; acc[g2 * 4 + 1] = ib.y;
                acc[g2 * 4 + 2] = ib.z; acc[g2 * 4 + 3] = ib.w;
            }
            __builtin_amdgcn_s_setprio(1);
            #pragma unroll
            for (int kk = 0; kk < 4; ++kk) {
                bf16x8 kb = *(const bf16x8*)&kl[col * 256 + (h * 8 + ((kk * 2 + hi) ^ (col & 7))) * 8];
                acc = __builtin_amdgcn_mfma_f32_32x32x16_bf16(qa[h][kk], kb, acc, 0, 0, 0);
            }
            __builtin_amdgcn_s_setprio(0);
            #pragma unroll
            for (int r = 0; r < 16; ++r) vsum[r] += exp2f(acc[r] * SCL2);
        }
        #pragma unroll
        for (int r = 0; r < 16; ++r) {
            int row = (r & 3) + 8 * (r >> 2) + 4 * hi;
            orow[(size_t)row * 1024 + key0 + kt * 32 + col] = vsum[r];
        }
        __syncthreads();
    }
}

// ---------------- K7: fused cheb + final with K-extension.
// acc = [badj | xg] @ [xt1 ; theta0]. out[b,e,c] = relu( xg[b,c,e] + relu(acc) ).
__global__ __launch_bounds__(256) void k_mm2(const float* __restrict__ badj,
                                             const ushort* __restrict__ xt1T,
                                             const ushort* __restrict__ Wcat,
                                             const ushort* __restrict__ xgb,
                                             float* __restrict__ out1) {
    __shared__ __align__(16) ushort smem[32768];
    int d = blockIdx.x;
    int xcd = d & 7, r = d >> 3;
    int lin = xcd * 64 + r;
    int b = lin >> 4, mt = (lin >> 1) & 7, nt = lin & 1;
    int m0 = mt * 128, n0 = nt * 128;
    int t = threadIdx.x, wid = t >> 6, l = t & 63;
    int ln = l & 31, hi = l >> 5;
    int wr = wid >> 1, wc = wid & 1;
    const float* Ab = badj + ((size_t)b << 20) + (size_t)m0 * 1024;
    const char* Bb  = (const char*)xt1T + (((size_t)(b * 256 + n0)) << 11);
    const char* Ab2 = (const char*)xgb + (size_t)(b * 1024 + m0) * 512;
    const char* Bb2 = (const char*)Wcat + (size_t)(512 + n0) * 512;
    int arow = t & 127, ahalf = t >> 7;
    const float* asrc = Ab + (size_t)arow * 1024 + ahalf * 32;
    f32x16 acc[2][2];
    #pragma unroll
    for (int i = 0; i < 2; ++i)
        #pragma unroll
        for (int j = 0; j < 2; ++j)
            #pragma unroll
            for (int q = 0; q < 16; ++q) acc[i][j][q] = 0.f;

    float4 ar[8];
    #pragma unroll
    for (int j = 0; j < 8; ++j) ar[j] = *(const float4*)(asrc + j * 4);
    stage16(Bb, 2048, smem + 8192, wid, l);
    {
        #pragma unroll
        for (int q = 0; q < 4; ++q) {
            union { unsigned u[4]; bf16x8 v; } pk;
            pk.u[0] = cvtpk(ar[2*q].x, ar[2*q].y);
            pk.u[1] = cvtpk(ar[2*q].z, ar[2*q].w);
            pk.u[2] = cvtpk(ar[2*q+1].x, ar[2*q+1].y);
            pk.u[3] = cvtpk(ar[2*q+1].z, ar[2*q+1].w);
            int cj = ahalf * 4 + q;
            *(bf16x8*)&smem[arow * 64 + ((cj ^ (arow & 7)) << 3)] = pk.v;
        }
    }
    __syncthreads();
    for (int kt = 0; kt < 20; ++kt) {
        const ushort* Al = smem + (kt & 1) * 16384;
        const ushort* Bl = Al + 8192;
        ushort* nb = smem + ((kt + 1) & 1) * 16384;
        int nk = kt + 1;
        if (nk < 16) {
            #pragma unroll
            for (int j = 0; j < 8; ++j) ar[j] = *(const float4*)(asrc + nk * 64 + j * 4);
            stage16(Bb + nk * 128, 2048, nb + 8192, wid, l);
        } else if (nk < 20) {
            stage16(Ab2 + (nk - 16) * 128, 512, nb, wid, l);
            stage16(Bb2 + (nk - 16) * 128, 512, nb + 8192, wid, l);
        }
        __builtin_amdgcn_s_setprio(1);
        #pragma unroll
        for (int ks = 0; ks < 4; ++ks) {
            int kc = ks * 2 + hi;
            int mr = wr * 64 + ln, nr = wc * 64 + ln;
            bf16x8 a0 = frag(Al, mr, kc);
            bf16x8 a1 = frag(Al, mr + 32, kc);
            bf16x8 b0 = frag(Bl, nr, kc);
            bf16x8 b1 = frag(Bl, nr + 32, kc);
            acc[0][0] = __builtin_amdgcn_mfma_f32_32x32x16_bf16(a0, b0, acc[0][0], 0, 0, 0);
            acc[0][1] = __builtin_amdgcn_mfma_f32_32x32x16_bf16(a0, b1, acc[0][1], 0, 0, 0);
            acc[1][0] = __builtin_amdgcn_mfma_f32_32x32x16_bf16(a1, b0, acc[1][0], 0, 0, 0);
            acc[1][1] = __builtin_amdgcn_mfma_f32_32x32x16_bf16(a1, b1, acc[1][1], 0, 0, 0);
        }
        __builtin_amdgcn_s_setprio(0);
        if (nk < 16) {
            #pragma unroll
            for (int q = 0; q < 4; ++q) {
                union { unsigned u[4]; bf16x8 v; } pk;
                pk.u[0] = cvtpk(ar[2*q].x, ar[2*q].y);
                pk.u[1] = cvtpk(ar[2*q].z, ar[2*q].w);
                pk.u[2] = cvtpk(ar[2*q+1].x, ar[2*q+1].y);
                pk.u[3] = cvtpk(ar[2*q+1].z, ar[2*q+1].w);
                int cj = ahalf * 4 + q;
                *(bf16x8*)&nb[arow * 64 + ((cj ^ (arow & 7)) << 3)] = pk.v;
            }
        }
        __syncthreads();
    }

    // ---- fused final epilogue ----
    int e0g = mt * 32;                       // = m0 >> 2
    ushort* xt_lds = smem;                   // [2 quadrants][128 n][32 e] pad 36
    for (int idx = t; idx < 4096; idx += 256) {
        int rr = idx >> 3, p = idx & 7;
        int q = rr >> 7, n = rr & 127;
        *(ushort4*)&xt_lds[(q * 128 + n) * 36 + p * 4] =
            *(const ushort4*)&xgb[((size_t)(b * 1024 + q * 256 + n0 + n)) * 256 + e0g + p * 4];
    }
    __syncthreads();
    #pragma unroll
    for (int mi = 0; mi < 2; ++mi)
        #pragma unroll
        for (int ni = 0; ni < 2; ++ni) {
            int nl = wc * 64 + ni * 32 + ln;
            #pragma unroll
            for (int r2 = 0; r2 < 4; ++r2) {
                int mbase = wr * 64 + mi * 32 + 8 * r2 + 4 * hi;
                int eloc = mbase >> 2;
                size_t obase = ((size_t)(b * 256 + e0g + eloc)) * 1024 + n0 + nl;
                #pragma unroll
                for (int j = 0; j < 4; ++j) {
                    float ch = acc[mi][ni][r2 * 4 + j];
                    float xv = bf2f(xt_lds[(j * 128 + nl) * 36 + eloc]);
                    float ov = fmaxf(xv + fmaxf(ch, 0.f), 0.f);
                    __builtin_nontemporal_store(ov, &out1[obase + (size_t)j * 256]);
                }
            }
        }
}

extern "C" void kernel_launch(void* const* d_in, const int* in_sizes, int n_in,
                              void* d_out, int out_size, void* d_ws, size_t ws_size,
                              hipStream_t stream) {
    const float* x     = (const float*)d_in[0];
    const float* w1    = (const float*)d_in[1];
    const float* w2    = (const float*)d_in[2];
    const float* wsi   = (const float*)d_in[3];
    const float* wqkv  = (const float*)d_in[4];
    const float* bqkv  = (const float*)d_in[5];
    const float* theta = (const float*)d_in[6];

    float* out1 = (float*)d_out;                     // first output [32,256,1024,1]
    float* badj = out1 + (size_t)BB * EE * CC;       // second output [32,1024,1024] fp32

    // workspace layout (bytes):
    //   xgb  bf16 [32768,256]   @ 0           (16,777,216)
    //   qk   bf16 [32768,512]   @ 16,777,216  (33,554,432)
    //   xt1T bf16 [32,256,1024] @ 67,108,864  (16,777,216)
    //   Wcat bf16 [1024,256]    @ 83,886,080  (524,288)
    //   sums fp32 [32768,4,4]   @ 84,410,368  (2,097,152)
    //   y0/yy fp32              @ 86,507,520  (2 x 131,072 within 3-slot region)
    //   wsb  bf16 [256,128]     @ 86,900,736  (65,536)
    char* wsb_ = (char*)d_ws;
    ushort* xgb  = (ushort*)(wsb_);
    ushort* qk   = (ushort*)(wsb_ + 16777216);
    ushort* xt1T = (ushort*)(wsb_ + 67108864);
    ushort* Wcat = (ushort*)(wsb_ + 83886080);
    float*  sums = (float*)(wsb_ + 84410368);
    float* y0 = (float*)(wsb_ + 86507520);
    float* yy = y0 + 65536;
    ushort* wsb = (ushort*)(wsb_ + 86900736);

    k_pool   <<<8192, 256, 0, stream>>>(x, y0);
    k_se     <<<320, 1024, 0, stream>>>(y0, w1, w2, yy, wqkv, theta, wsi, Wcat, wsb);
    k_conv   <<<512,  256, 0, stream>>>(x, wsb, yy, xgb);
    k_mm1    <<<1536, 256, 0, stream>>>(xgb, Wcat, bqkv, qk, xt1T);
    k_attn_s <<<2048, 256, 0, stream>>>(qk, sums);
    k_attn_w <<<1024, 256, 0, stream>>>(qk, sums, badj);
    k_mm2    <<<512,  256, 0, stream>>>(badj, xt1T, Wcat, xgb, out1);
}

// Round 13
// 209.468 us; speedup vs baseline: 2.0113x; 2.0113x over previous
//
#include <hip/hip_runtime.h>

#define BB 32
#define CC 1024
#define EE 256

typedef __attribute__((ext_vector_type(8))) short bf16x8;
typedef __attribute__((ext_vector_type(16))) float f32x16;

__device__ __forceinline__ ushort f2bf(float f) {
    unsigned u = __float_as_uint(f);
    unsigned r = (u + 0x7FFFu + ((u >> 16) & 1u)) >> 16;
    return (ushort)r;
}
__device__ __forceinline__ float bf2f(ushort u) { return __uint_as_float((unsigned)u << 16); }

// packed f32x2 -> bf16x2 (RNE, identical to f2bf) — no builtin on gfx950, use asm
__device__ __forceinline__ unsigned cvtpk(float lo, float hi) {
    unsigned r;
    asm("v_cvt_pk_bf16_f32 %0, %1, %2" : "=v"(r) : "v"(lo), "v"(hi));
    return r;
}

// stage 128 rows x 64 bf16 (128B) from global into 16KB LDS, source pre-swizzled so that
// ds_read with chunk ^= (row&7) returns linear data. LDS dest must be wave-uniform.
__device__ __forceinline__ void stage16(const char* srcBase, long stride, ushort* ldsBase,
                                        int wid, int lane) {
    #pragma unroll
    for (int i = 0; i < 4; ++i) {
        int gch = (wid * 4 + i) * 64 + lane;
        int row = gch >> 3, cj = gch & 7;
        const char* src = srcBase + (long)row * stride + ((cj ^ (row & 7)) << 4);
        __builtin_amdgcn_global_load_lds(
            (const __attribute__((address_space(1))) unsigned*)src,
            (__attribute__((address_space(3))) unsigned*)(ldsBase + (wid * 4 + i) * 512),
            16, 0, 0);
    }
}

__device__ __forceinline__ bf16x8 frag(const ushort* L, int row, int kc) {
    return *(const bf16x8*)&L[row * 64 + ((kc ^ (row & 7)) << 3)];
}

// ---------------- K1: SE adaptive-avg-pool (+ merged Wcat/wsb prep in tail blocks)
__global__ __launch_bounds__(256) void k_pool(const float* __restrict__ x,
                                              float* __restrict__ y0,
                                              const float* __restrict__ W,
                                              const float* __restrict__ theta,
                                              const float* __restrict__ wsi,
                                              ushort* __restrict__ Wcat,
                                              ushort* __restrict__ wsb) {
    int t = threadIdx.x;
    if (blockIdx.x >= 8192) {
        int idx = (blockIdx.x - 8192) * 256 + t;
        if (idx < 262144) {
            int n = idx >> 8, k = idx & 255;
            float v;
            if (n < 512) v = W[n * 256 + k];
            else if (n < 768) v = theta[k * 256 + (n - 512)];
            else v = theta[65536 + k * 256 + (n - 768)];
            Wcat[idx] = f2bf(v);
        } else {
            int i2 = idx - 262144;          // 0..32767 -> ws [256 e][128 l] plain bf16
            wsb[i2] = f2bf(wsi[i2]);
        }
        return;
    }
    int lane = t & 63;
    int v = blockIdx.x * 4 + (t >> 6);
    const float2* p = (const float2*)(x + (size_t)v * 128);
    float2 d = p[lane];
    float s = d.x + d.y;
    #pragma unroll
    for (int m = 1; m < 64; m <<= 1) s += __shfl_xor(s, m, 64);
    if (lane == 0) y0[v] = s * (1.0f / 128.0f);
}

// ---------------- K2/K3: SE fc layers — wave-per-output, coalesced K-split.
// grid 2048: block = 4 waves x 4 outputs = 16 outputs; 64 blocks per batch.
template <int ACT>   // 0 = relu, 1 = sigmoid
__global__ __launch_bounds__(256) void k_se_fc(const float* __restrict__ in,
                                               const float* __restrict__ w,
                                               float* __restrict__ outp) {
    __shared__ float yin[1024];
    int t = threadIdx.x, wv = t >> 6, lane = t & 63;
    int b = blockIdx.x >> 6;
    int i0 = (blockIdx.x & 63) * 16 + wv * 4;
    for (int k = t; k < 1024; k += 256) yin[k] = in[b * 1024 + k];
    __syncthreads();
    #pragma unroll
    for (int o = 0; o < 4; ++o) {
        int i = i0 + o;
        const float4* wr = (const float4*)(w + (size_t)i * 1024);
        float acc = 0.f;
        #pragma unroll
        for (int j = 0; j < 4; ++j) {
            float4 wv4 = wr[j * 64 + lane];              // coalesced: 1KB per instr
            const float* yv = &yin[(j * 64 + lane) * 4];
            acc += wv4.x * yv[0] + wv4.y * yv[1] + wv4.z * yv[2] + wv4.w * yv[3];
        }
        #pragma unroll
        for (int m = 1; m < 64; m <<= 1) acc += __shfl_xor(acc, m, 64);
        if (lane == 0) {
            float r = (ACT == 0) ? fmaxf(acc, 0.f) : (1.f / (1.f + expf(-acc)));
            outp[b * 1024 + i] = r;
        }
    }
}

// ---------------- K4: SE-scale + 1x1 conv as MFMA GEMM.
// Block (b, 64-c tile): xg[c,e] = sum_l (x[l,c]*y[8l+cb]) * ws[e,l].
__global__ __launch_bounds__(256) void k_conv(const float* __restrict__ x,
                                              const ushort* __restrict__ wsb,
                                              const float* __restrict__ y,
                                              ushort* __restrict__ xgb) {
    __shared__ __align__(16) ushort wsB[256 * 64];   // [e][l-half] swizzled, 32KB
    __shared__ __align__(16) ushort xfB[64 * 72];    // [l-half][c] staging, 9KB
    __shared__ __align__(16) ushort xT[64 * 64];     // [c][l-half] swizzled, 8KB
    __shared__ float sl[128];
    int bid = blockIdx.x;
    int b = bid >> 4, ct = bid & 15;
    int c0 = ct * 64, cb = ct >> 1;
    int t = threadIdx.x, wid = t >> 6, l = t & 63;
    int ln = l & 31, hi = l >> 5;

    if (t < 128) sl[t] = y[b * 1024 + 8 * t + cb];

    f32x16 acc[2][2];
    #pragma unroll
    for (int i = 0; i < 2; ++i)
        #pragma unroll
        for (int j = 0; j < 2; ++j)
            #pragma unroll
            for (int q = 0; q < 16; ++q) acc[i][j][q] = 0.f;

    for (int ph = 0; ph < 2; ++ph) {
        int lh = ph * 64;
        __syncthreads();
        #pragma unroll
        for (int i = 0; i < 8; ++i) {
            int gch = i * 256 + wid * 64 + l;
            int e = gch >> 3, cj = gch & 7;
            const ushort* src = wsb + e * 128 + lh + ((cj ^ (e & 7)) << 3);
            __builtin_amdgcn_global_load_lds(
                (const __attribute__((address_space(1))) unsigned*)src,
                (__attribute__((address_space(3))) unsigned*)(wsB + gch * 8),
                16, 0, 0);
        }
        #pragma unroll
        for (int i = 0; i < 4; ++i) {
            int chunk = i * 256 + t;
            int lr = chunk >> 4, cq = chunk & 15;
            float4 v = *(const float4*)&x[(size_t)b * 131072 + (size_t)(lh + lr) * 1024 + c0 + cq * 4];
            float s = sl[lh + lr];
            uint2 pk;
            pk.x = cvtpk(v.x * s, v.y * s);
            pk.y = cvtpk(v.z * s, v.w * s);
            *(uint2*)&xfB[lr * 72 + cq * 4] = pk;
        }
        __syncthreads();
        {
            int c = t & 63, lq = t >> 6;
            #pragma unroll
            for (int q2 = 0; q2 < 2; ++q2) {
                int cj = lq * 2 + q2;
                bf16x8 pk;
                #pragma unroll
                for (int jj = 0; jj < 8; ++jj)
                    pk[jj] = (short)xfB[(cj * 8 + jj) * 72 + c];
                *(bf16x8*)&xT[c * 64 + ((cj ^ (c & 7)) << 3)] = pk;
            }
        }
        __syncthreads();
        __builtin_amdgcn_s_setprio(1);
        #pragma unroll
        for (int ks = 0; ks < 4; ++ks) {
            int kc = ks * 2 + hi;
            bf16x8 a0 = frag(xT, ln, kc);
            bf16x8 a1 = frag(xT, ln + 32, kc);
            bf16x8 b0 = frag(wsB, wid * 64 + ln, kc);
            bf16x8 b1 = frag(wsB, wid * 64 + 32 + ln, kc);
            acc[0][0] = __builtin_amdgcn_mfma_f32_32x32x16_bf16(a0, b0, acc[0][0], 0, 0, 0);
            acc[0][1] = __builtin_amdgcn_mfma_f32_32x32x16_bf16(a0, b1, acc[0][1], 0, 0, 0);
            acc[1][0] = __builtin_amdgcn_mfma_f32_32x32x16_bf16(a1, b0, acc[1][0], 0, 0, 0);
            acc[1][1] = __builtin_amdgcn_mfma_f32_32x32x16_bf16(a1, b1, acc[1][1], 0, 0, 0);
        }
        __builtin_amdgcn_s_setprio(0);
    }
    #pragma unroll
    for (int mi = 0; mi < 2; ++mi)
        #pragma unroll
        for (int ni = 0; ni < 2; ++ni) {
            int e = wid * 64 + ni * 32 + ln;
            #pragma unroll
            for (int r2 = 0; r2 < 4; ++r2)
                #pragma unroll
                for (int j = 0; j < 4; ++j) {
                    int cloc = mi * 32 + 8 * r2 + 4 * hi + j;
                    xgb[(size_t)(b * 1024 + c0 + cloc) * 256 + e] = f2bf(acc[mi][ni][r2 * 4 + j]);
                }
        }
}

// ---------------- K5: projection GEMM (qk + xt1T only; xt0 folded into mm2).
// grid 1536: 6 n-tiles per 128-row m-strip. nt<4 -> qk(+bias), nt 4,5 -> xt1T.
// xt1T tiles read theta1 rows of Wcat (768+): B row base n0+256.
__global__ __launch_bounds__(256) void k_mm1(const ushort* __restrict__ xgb,
                                             const ushort* __restrict__ Wcat,
                                             const float* __restrict__ bias,
                                             ushort* __restrict__ qk,
                                             ushort* __restrict__ xt1T) {
    __shared__ __align__(16) ushort smem[32768];   // 2 bufs x (Al 8192 + Bl 8192)
    int d = blockIdx.x;
    int xcd = d & 7, r = d >> 3;
    int q6 = r / 6;
    int mt = xcd * 32 + q6, nt = r - q6 * 6;
    int m0 = mt * 128, n0 = nt * 128;
    int bn0 = (nt < 4) ? n0 : n0 + 256;            // theta1 rows for xt1T tiles
    int t = threadIdx.x, wid = t >> 6, l = t & 63;
    int ln = l & 31, hi = l >> 5;
    int wr = wid >> 1, wc = wid & 1;
    const char* Ab = (const char*)xgb + (size_t)m0 * 512;
    const char* Bb = (const char*)Wcat + (size_t)bn0 * 512;
    f32x16 acc[2][2];
    #pragma unroll
    for (int i = 0; i < 2; ++i)
        #pragma unroll
        for (int j = 0; j < 2; ++j)
            #pragma unroll
            for (int q = 0; q < 16; ++q) acc[i][j][q] = 0.f;

    stage16(Ab, 512, smem, wid, l);
    stage16(Bb, 512, smem + 8192, wid, l);
    __syncthreads();
    for (int kt = 0; kt < 4; ++kt) {
        const ushort* Al = smem + (kt & 1) * 16384;
        const ushort* Bl = Al + 8192;
        if (kt < 3) {
            ushort* nb = smem + ((kt + 1) & 1) * 16384;
            stage16(Ab + (kt + 1) * 128, 512, nb, wid, l);
            stage16(Bb + (kt + 1) * 128, 512, nb + 8192, wid, l);
        }
        __builtin_amdgcn_s_setprio(1);
        #pragma unroll
        for (int ks = 0; ks < 4; ++ks) {
            int kc = ks * 2 + hi;
            int mr = wr * 64 + ln, nr = wc * 64 + ln;
            bf16x8 a0 = frag(Al, mr, kc);
            bf16x8 a1 = frag(Al, mr + 32, kc);
            bf16x8 b0 = frag(Bl, nr, kc);
            bf16x8 b1 = frag(Bl, nr + 32, kc);
            acc[0][0] = __builtin_amdgcn_mfma_f32_32x32x16_bf16(a0, b0, acc[0][0], 0, 0, 0);
            acc[0][1] = __builtin_amdgcn_mfma_f32_32x32x16_bf16(a0, b1, acc[0][1], 0, 0, 0);
            acc[1][0] = __builtin_amdgcn_mfma_f32_32x32x16_bf16(a1, b0, acc[1][0], 0, 0, 0);
            acc[1][1] = __builtin_amdgcn_mfma_f32_32x32x16_bf16(a1, b1, acc[1][1], 0, 0, 0);
        }
        __builtin_amdgcn_s_setprio(0);
        __syncthreads();
    }
    if (nt < 4) {
        float bv[2];
        bv[0] = bias[nt * 128 + wc * 64 + ln];
        bv[1] = bias[nt * 128 + wc * 64 + 32 + ln];
        #pragma unroll
        for (int mi = 0; mi < 2; ++mi)
            #pragma unroll
            for (int ni = 0; ni < 2; ++ni) {
                int ncol = wc * 64 + ni * 32 + ln;
                #pragma unroll
                for (int r2 = 0; r2 < 4; ++r2)
                    #pragma unroll
                    for (int j = 0; j < 4; ++j) {
                        int mloc = wr * 64 + mi * 32 + 8 * r2 + 4 * hi + j;
                        float v = acc[mi][ni][r2 * 4 + j] + bv[ni];
                        size_t m = (size_t)(m0 + mloc);
                        qk[m * 512 + nt * 128 + ncol] = f2bf(v);
                    }
            }
    } else {
        ushort* Tl = smem;   // [128][136]
        #pragma unroll
        for (int mi = 0; mi < 2; ++mi)
            #pragma unroll
            for (int ni = 0; ni < 2; ++ni) {
                int nl = wc * 64 + ni * 32 + ln;
                #pragma unroll
                for (int r2 = 0; r2 < 4; ++r2) {
                    int mbase = wr * 64 + mi * 32 + 8 * r2 + 4 * hi;
                    ushort4 pk = make_ushort4(f2bf(acc[mi][ni][r2 * 4 + 0]),
                                              f2bf(acc[mi][ni][r2 * 4 + 1]),
                                              f2bf(acc[mi][ni][r2 * 4 + 2]),
                                              f2bf(acc[mi][ni][r2 * 4 + 3]));
                    *(ushort4*)&Tl[nl * 136 + mbase] = pk;
                }
            }
        __syncthreads();
        int n = t >> 1, mh = (t & 1) * 64;
        int bq = m0 >> 10, mib = m0 & 1023;
        ushort* dst = xt1T + (((size_t)(bq * 256 + (nt - 4) * 128 + n)) << 10) + mib + mh;
        #pragma unroll
        for (int j = 0; j < 8; ++j)
            *(uint4*)(dst + j * 8) = *(const uint4*)&Tl[n * 136 + mh + j * 8];
    }
}

// ---------------- K6a: attention partial exp-sums (head-pair split).
// grid 2048. XCD-local decode: bid&7 = b&7.
__global__ __launch_bounds__(256, 3) void k_attn_s(const ushort* __restrict__ qkb,
                                                   float* __restrict__ sums) {
    __shared__ __align__(16) ushort klds[2][4096];       // [buf][32 keys][128 d swz]
    const float SCL2 = 0.18033688011112042f;             // log2(e)/8
    int bid = blockIdx.x;
    int b = ((bid >> 3) & 3) * 8 + (bid & 7);
    int hp = (bid >> 5) & 1;
    int kh = (bid >> 6) & 3;
    int qt = bid >> 8;
    int t = threadIdx.x, g = t >> 6, l = t & 63;
    int wid = g;
    int col = l & 31, hi = l >> 5;
    size_t qbase = (size_t)b * 1024 * 512;
    int qrow = qt * 128 + g * 32 + col;
    int key0 = kh * 256;

    bf16x8 qa[2][4];
    #pragma unroll
    for (int hh = 0; hh < 2; ++hh)
        #pragma unroll
        for (int kk = 0; kk < 4; ++kk)
            qa[hh][kk] = *(const bf16x8*)&qkb[qbase + (size_t)qrow * 512 +
                                             (hp * 2 + hh) * 64 + kk * 16 + hi * 8];

    const char* kgb = (const char*)(qkb + qbase + 256 + hp * 128);
    auto stage_k = [&](int kt, ushort* dst) {
        #pragma unroll
        for (int i = 0; i < 2; ++i) {
            int gidx = i * 256 + wid * 64 + l;
            int row = gidx >> 4, c = gidx & 15;
            const char* src = kgb + (size_t)(key0 + kt * 32 + row) * 1024 +
                              (((c >> 3) << 7) + (((c & 7) ^ (row & 7)) << 4));
            __builtin_amdgcn_global_load_lds(
                (const __attribute__((address_space(1))) unsigned*)src,
                (__attribute__((address_space(3))) unsigned*)(dst + (i * 256 + wid * 64) * 8),
                16, 0, 0);
        }
    };

    float prsum[2][16];
    #pragma unroll
    for (int hh = 0; hh < 2; ++hh)
        #pragma unroll
        for (int r = 0; r < 16; ++r) prsum[hh][r] = 0.f;

    stage_k(0, klds[0]);
    __syncthreads();
    for (int kt = 0; kt < 8; ++kt) {
        if (kt < 7) stage_k(kt + 1, klds[(kt + 1) & 1]);
        const ushort* kl = &klds[kt & 1][0];
        f32x16 acc[2];
        #pragma unroll
        for (int hh = 0; hh < 2; ++hh)
            #pragma unroll
            for (int r = 0; r < 16; ++r) acc[hh][r] = 0.f;
        __builtin_amdgcn_s_setprio(1);
        #pragma unroll
        for (int kk = 0; kk < 4; ++kk) {
            #pragma unroll
            for (int hh = 0; hh < 2; ++hh) {
                bf16x8 kb = *(const bf16x8*)&kl[col * 128 +
                                               (hh * 8 + ((kk * 2 + hi) ^ (col & 7))) * 8];
                acc[hh] = __builtin_amdgcn_mfma_f32_32x32x16_bf16(qa[hh][kk], kb, acc[hh], 0, 0, 0);
            }
        }
        __builtin_amdgcn_s_setprio(0);
        #pragma unroll
        for (int hh = 0; hh < 2; ++hh)
            #pragma unroll
            for (int r = 0; r < 16; ++r)
                prsum[hh][r] += exp2f(acc[hh][r] * SCL2);
        __syncthreads();
    }
    #pragma unroll
    for (int hh = 0; hh < 2; ++hh)
        #pragma unroll
        for (int r = 0; r < 16; ++r) {
            float s = prsum[hh][r];
            s += __shfl_xor(s, 1, 64);
            s += __shfl_xor(s, 2, 64);
            s += __shfl_xor(s, 4, 64);
            s += __shfl_xor(s, 8, 64);
            s += __shfl_xor(s, 16, 64);
            prsum[hh][r] = s;
        }
    if (col == 0) {
        int rowbase = qt * 128 + g * 32 + 4 * hi;
        #pragma unroll
        for (int hh = 0; hh < 2; ++hh)
            #pragma unroll
            for (int r = 0; r < 16; ++r) {
                int row = rowbase + (r & 3) + 8 * (r >> 2);
                sums[(((size_t)b * 1024 + row) * 4 + hp * 2 + hh) * 4 + kh] = prsum[hh][r];
            }
    }
}

// ---------------- K6b: attention normalize + write b_adj fp32.
// grid 1024, XCD-local. Head-sequential MFMA with C-init log-bias.
__global__ __launch_bounds__(256, 3) void k_attn_w(const ushort* __restrict__ qkb,
                                                   const float* __restrict__ sums,
                                                   float* __restrict__ badj) {
    __shared__ __align__(16) ushort klds[2][8192];
    __shared__ __align__(16) float biasB[4][128];
    const float SCL2 = 0.18033688011112042f;
    const float INV_SCL2 = 5.545177444479562f;           // 1/SCL2
    int bid = blockIdx.x;
    int b = ((bid >> 3) & 3) * 8 + (bid & 7);
    int kh = (bid >> 5) & 3;
    int qt = bid >> 7;
    int t = threadIdx.x, g = t >> 6, l = t & 63;
    int wid = g;
    int col = l & 31, hi = l >> 5;
    size_t qbase = (size_t)b * 1024 * 512;
    int qrow = qt * 128 + g * 32 + col;
    int key0 = kh * 256;

    {
        const float4* sp = (const float4*)(sums + ((size_t)b * 1024 + qt * 128) * 16);
        #pragma unroll
        for (int i = 0; i < 2; ++i) {
            int f = t * 2 + i;
            float4 v = sp[f];
            float s4 = v.x + v.y + v.z + v.w;
            biasB[f & 3][f >> 2] = -(__log2f(s4) + 2.0f) * INV_SCL2;
        }
    }

    bf16x8 qa[4][4];
    #pragma unroll
    for (int h = 0; h < 4; ++h)
        #pragma unroll
        for (int kk = 0; kk < 4; ++kk)
            qa[h][kk] = *(const bf16x8*)&qkb[qbase + (size_t)qrow * 512 + h * 64 + kk * 16 + hi * 8];

    const char* kgb = (const char*)(qkb + qbase + 256);
    auto stage_k = [&](int kt, ushort* dst) {
        #pragma unroll
        for (int i = 0; i < 4; ++i) {
            int gidx = i * 256 + wid * 64 + l;
            int row = gidx >> 5, c = gidx & 31;
            const char* src = kgb + (size_t)(key0 + kt * 32 + row) * 1024 +
                              (((c >> 3) << 7) + (((c & 7) ^ (row & 7)) << 4));
            __builtin_amdgcn_global_load_lds(
                (const __attribute__((address_space(1))) unsigned*)src,
                (__attribute__((address_space(3))) unsigned*)(dst + (i * 256 + wid * 64) * 8),
                16, 0, 0);
        }
    };

    stage_k(0, klds[0]);
    __syncthreads();

    float* orow = badj + ((size_t)b << 20) + (size_t)(qt * 128 + g * 32) * 1024;
    for (int kt = 0; kt < 8; ++kt) {
        if (kt < 7) stage_k(kt + 1, klds[(kt + 1) & 1]);
        const ushort* kl = &klds[kt & 1][0];
        float vsum[16];
        #pragma unroll
        for (int r = 0; r < 16; ++r) vsum[r] = 0.f;
        #pragma unroll
        for (int h = 0; h < 4; ++h) {
            f32x16 acc;
            #pragma unroll
            for (int g2 = 0; g2 < 4; ++g2) {
                float4 ib = *(const float4*)&biasB[h][g * 32 + g2 * 8 + 4 * hi];
                acc[g2 * 4 + 0] = ib.x; acc[g2 * 4 + 1] = ib.y;
                acc[g2 * 4 + 2] = ib.z; acc[g2 * 4 + 3] = ib.w;
            }
            __builtin_amdgcn_s_setprio(1);
            #pragma unroll
            for (int kk = 0; kk < 4; ++kk) {
                bf16x8 kb = *(const bf16x8*)&kl[col * 256 + (h * 8 + ((kk * 2 + hi) ^ (col & 7))) * 8];
                acc = __builtin_amdgcn_mfma_f32_32x32x16_bf16(qa[h][kk], kb, acc, 0, 0, 0);
            }
            __builtin_amdgcn_s_setprio(0);
            #pragma unroll
            for (int r = 0; r < 16; ++r) vsum[r] += exp2f(acc[r] * SCL2);
        }
        #pragma unroll
        for (int r = 0; r < 16; ++r) {
            int row = (r & 3) + 8 * (r >> 2) + 4 * hi;
            orow[(size_t)row * 1024 + key0 + kt * 32 + col] = vsum[r];
        }
        __syncthreads();
    }
}

// ---------------- K7: fused cheb + final with K-extension.
// acc = [badj | xg] @ [xt1 ; theta0]. out[b,e,c] = relu( xg[b,c,e] + relu(acc) ).
__global__ __launch_bounds__(256) void k_mm2(const float* __restrict__ badj,
                                             const ushort* __restrict__ xt1T,
                                             const ushort* __restrict__ Wcat,
                                             const ushort* __restrict__ xgb,
                                             float* __restrict__ out1) {
    __shared__ __align__(16) ushort smem[32768];
    int d = blockIdx.x;
    int xcd = d & 7, r = d >> 3;
    int lin = xcd * 64 + r;
    int b = lin >> 4, mt = (lin >> 1) & 7, nt = lin & 1;
    int m0 = mt * 128, n0 = nt * 128;
    int t = threadIdx.x, wid = t >> 6, l = t & 63;
    int ln = l & 31, hi = l >> 5;
    int wr = wid >> 1, wc = wid & 1;
    const float* Ab = badj + ((size_t)b << 20) + (size_t)m0 * 1024;
    const char* Bb  = (const char*)xt1T + (((size_t)(b * 256 + n0)) << 11);
    const char* Ab2 = (const char*)xgb + (size_t)(b * 1024 + m0) * 512;
    const char* Bb2 = (const char*)Wcat + (size_t)(512 + n0) * 512;
    int arow = t & 127, ahalf = t >> 7;
    const float* asrc = Ab + (size_t)arow * 1024 + ahalf * 32;
    f32x16 acc[2][2];
    #pragma unroll
    for (int i = 0; i < 2; ++i)
        #pragma unroll
        for (int j = 0; j < 2; ++j)
            #pragma unroll
            for (int q = 0; q < 16; ++q) acc[i][j][q] = 0.f;

    float4 ar[8];
    #pragma unroll
    for (int j = 0; j < 8; ++j) ar[j] = *(const float4*)(asrc + j * 4);
    stage16(Bb, 2048, smem + 8192, wid, l);
    {
        #pragma unroll
        for (int q = 0; q < 4; ++q) {
            union { unsigned u[4]; bf16x8 v; } pk;
            pk.u[0] = cvtpk(ar[2*q].x, ar[2*q].y);
            pk.u[1] = cvtpk(ar[2*q].z, ar[2*q].w);
            pk.u[2] = cvtpk(ar[2*q+1].x, ar[2*q+1].y);
            pk.u[3] = cvtpk(ar[2*q+1].z, ar[2*q+1].w);
            int cj = ahalf * 4 + q;
            *(bf16x8*)&smem[arow * 64 + ((cj ^ (arow & 7)) << 3)] = pk.v;
        }
    }
    __syncthreads();
    for (int kt = 0; kt < 20; ++kt) {
        const ushort* Al = smem + (kt & 1) * 16384;
        const ushort* Bl = Al + 8192;
        ushort* nb = smem + ((kt + 1) & 1) * 16384;
        int nk = kt + 1;
        if (nk < 16) {
            #pragma unroll
            for (int j = 0; j < 8; ++j) ar[j] = *(const float4*)(asrc + nk * 64 + j * 4);
            stage16(Bb + nk * 128, 2048, nb + 8192, wid, l);
        } else if (nk < 20) {
            stage16(Ab2 + (nk - 16) * 128, 512, nb, wid, l);
            stage16(Bb2 + (nk - 16) * 128, 512, nb + 8192, wid, l);
        }
        __builtin_amdgcn_s_setprio(1);
        #pragma unroll
        for (int ks = 0; ks < 4; ++ks) {
            int kc = ks * 2 + hi;
            int mr = wr * 64 + ln, nr = wc * 64 + ln;
            bf16x8 a0 = frag(Al, mr, kc);
            bf16x8 a1 = frag(Al, mr + 32, kc);
            bf16x8 b0 = frag(Bl, nr, kc);
            bf16x8 b1 = frag(Bl, nr + 32, kc);
            acc[0][0] = __builtin_amdgcn_mfma_f32_32x32x16_bf16(a0, b0, acc[0][0], 0, 0, 0);
            acc[0][1] = __builtin_amdgcn_mfma_f32_32x32x16_bf16(a0, b1, acc[0][1], 0, 0, 0);
            acc[1][0] = __builtin_amdgcn_mfma_f32_32x32x16_bf16(a1, b0, acc[1][0], 0, 0, 0);
            acc[1][1] = __builtin_amdgcn_mfma_f32_32x32x16_bf16(a1, b1, acc[1][1], 0, 0, 0);
        }
        __builtin_amdgcn_s_setprio(0);
        if (nk < 16) {
            #pragma unroll
            for (int q = 0; q < 4; ++q) {
                union { unsigned u[4]; bf16x8 v; } pk;
                pk.u[0] = cvtpk(ar[2*q].x, ar[2*q].y);
                pk.u[1] = cvtpk(ar[2*q].z, ar[2*q].w);
                pk.u[2] = cvtpk(ar[2*q+1].x, ar[2*q+1].y);
                pk.u[3] = cvtpk(ar[2*q+1].z, ar[2*q+1].w);
                int cj = ahalf * 4 + q;
                *(bf16x8*)&nb[arow * 64 + ((cj ^ (arow & 7)) << 3)] = pk.v;
            }
        }
        __syncthreads();
    }

    // ---- fused final epilogue ----
    int e0g = mt * 32;                       // = m0 >> 2
    ushort* xt_lds = smem;                   // [2 quadrants][128 n][32 e] pad 36
    for (int idx = t; idx < 4096; idx += 256) {
        int rr = idx >> 3, p = idx & 7;
        int q = rr >> 7, n = rr & 127;
        *(ushort4*)&xt_lds[(q * 128 + n) * 36 + p * 4] =
            *(const ushort4*)&xgb[((size_t)(b * 1024 + q * 256 + n0 + n)) * 256 + e0g + p * 4];
    }
    __syncthreads();
    #pragma unroll
    for (int mi = 0; mi < 2; ++mi)
        #pragma unroll
        for (int ni = 0; ni < 2; ++ni) {
            int nl = wc * 64 + ni * 32 + ln;
            #pragma unroll
            for (int r2 = 0; r2 < 4; ++r2) {
                int mbase = wr * 64 + mi * 32 + 8 * r2 + 4 * hi;
                int eloc = mbase >> 2;
                size_t obase = ((size_t)(b * 256 + e0g + eloc)) * 1024 + n0 + nl;
                #pragma unroll
                for (int j = 0; j < 4; ++j) {
                    float ch = acc[mi][ni][r2 * 4 + j];
                    float xv = bf2f(xt_lds[(j * 128 + nl) * 36 + eloc]);
                    float ov = fmaxf(xv + fmaxf(ch, 0.f), 0.f);
                    __builtin_nontemporal_store(ov, &out1[obase + (size_t)j * 256]);
                }
            }
        }
}

extern "C" void kernel_launch(void* const* d_in, const int* in_sizes, int n_in,
                              void* d_out, int out_size, void* d_ws, size_t ws_size,
                              hipStream_t stream) {
    const float* x     = (const float*)d_in[0];
    const float* w1    = (const float*)d_in[1];
    const float* w2    = (const float*)d_in[2];
    const float* wsi   = (const float*)d_in[3];
    const float* wqkv  = (const float*)d_in[4];
    const float* bqkv  = (const float*)d_in[5];
    const float* theta = (const float*)d_in[6];

    float* out1 = (float*)d_out;                     // first output [32,256,1024,1]
    float* badj = out1 + (size_t)BB * EE * CC;       // second output [32,1024,1024] fp32

    // workspace layout (bytes):
    //   xgb  bf16 [32768,256]   @ 0           (16,777,216)
    //   qk   bf16 [32768,512]   @ 16,777,216  (33,554,432)
    //   xt1T bf16 [32,256,1024] @ 67,108,864  (16,777,216)
    //   Wcat bf16 [1024,256]    @ 83,886,080  (524,288)
    //   sums fp32 [32768,4,4]   @ 84,410,368  (2,097,152)
    //   y0/hh/yy fp32           @ 86,507,520  (3 x 131,072)
    //   wsb  bf16 [256,128]     @ 86,900,736  (65,536)
    char* wsb_ = (char*)d_ws;
    ushort* xgb  = (ushort*)(wsb_);
    ushort* qk   = (ushort*)(wsb_ + 16777216);
    ushort* xt1T = (ushort*)(wsb_ + 67108864);
    ushort* Wcat = (ushort*)(wsb_ + 83886080);
    float*  sums = (float*)(wsb_ + 84410368);
    float* y0 = (float*)(wsb_ + 86507520);
    float* hh = y0 + 32768;
    float* yy = y0 + 65536;
    ushort* wsb = (ushort*)(wsb_ + 86900736);

    k_pool   <<<9344, 256, 0, stream>>>(x, y0, wqkv, theta, wsi, Wcat, wsb);
    k_se_fc<0><<<2048, 256, 0, stream>>>(y0, w1, hh);
    k_se_fc<1><<<2048, 256, 0, stream>>>(hh, w2, yy);
    k_conv   <<<512,  256, 0, stream>>>(x, wsb, yy, xgb);
    k_mm1    <<<1536, 256, 0, stream>>>(xgb, Wcat, bqkv, qk, xt1T);
    k_attn_s <<<2048, 256, 0, stream>>>(qk, sums);
    k_attn_w <<<1024, 256, 0, stream>>>(qk, sums, badj);
    k_mm2    <<<512,  256, 0, stream>>>(badj, xt1T, Wcat, xgb, out1);
}